// Round 3
// baseline (669.714 us; speedup 1.0000x reference)
//
#include <hip/hip_runtime.h>
#include <cstdint>
#include <cmath>

#define B_    16
#define S_    1024
#define H_    32
#define D_    128
#define HID   4096
#define INTER 11008
#define NC    8         // attention sequence chunks
#define CHUNK 128       // S_/NC

// ---------------------------------------------------------------- RMSNorm
__global__ __launch_bounds__(256) void rmsnorm_kernel(
    const float* __restrict__ in, const float* __restrict__ w, float* __restrict__ out)
{
    int b = blockIdx.x;
    int t = threadIdx.x;
    const float4* row = reinterpret_cast<const float4*>(in + (size_t)b * HID);
    float s = 0.f;
    for (int i = t; i < HID / 4; i += 256) {
        float4 v = row[i];
        s += v.x * v.x + v.y * v.y + v.z * v.z + v.w * v.w;
    }
    for (int off = 32; off; off >>= 1) s += __shfl_down(s, off, 64);
    __shared__ float red[4];
    int wid = t >> 6, lane = t & 63;
    if (lane == 0) red[wid] = s;
    __syncthreads();
    float tot = red[0] + red[1] + red[2] + red[3];
    float rstd = rsqrtf(tot / (float)HID + 1e-6f);
    const float4* wv4 = reinterpret_cast<const float4*>(w);
    float4* o4 = reinterpret_cast<float4*>(out + (size_t)b * HID);
    for (int i = t; i < HID / 4; i += 256) {
        float4 x = row[i], wv = wv4[i];
        float4 r;
        r.x = x.x * rstd * wv.x;
        r.y = x.y * rstd * wv.y;
        r.z = x.z * rstd * wv.z;
        r.w = x.w * rstd * wv.w;
        o4[i] = r;
    }
}

// ---------------------------------------------- skinny GEMM, split-K, float2 cols
// thread owns 2 consecutive output columns; x chunk staged in LDS ([b][kc] natural,
// per-k reads are wave-uniform broadcasts -> bank-conflict-free by definition)
__global__ __launch_bounds__(256) void gemm16_splitk2(
    const float* __restrict__ x, const float* __restrict__ w,
    float* __restrict__ part, int K, int N, int kchunk)
{
    int j0 = (blockIdx.x * 256 + threadIdx.x) * 2;   // grids sized exactly
    int k0 = blockIdx.y * kchunk;
    int kc = min(K - k0, kchunk);
    extern __shared__ float x_lds[];                 // [16][kc]
#pragma unroll
    for (int b = 0; b < B_; ++b)
        for (int kk = threadIdx.x; kk < kc; kk += 256)
            x_lds[b * kc + kk] = x[(size_t)b * K + k0 + kk];
    __syncthreads();

    float2 acc[B_];
#pragma unroll
    for (int b = 0; b < B_; ++b) acc[b] = make_float2(0.f, 0.f);

    const float* wp = w + (size_t)k0 * N + j0;
#pragma unroll 4
    for (int kk = 0; kk < kc; ++kk) {
        float2 wv = *reinterpret_cast<const float2*>(wp);
        wp += N;
#pragma unroll
        for (int b = 0; b < B_; ++b) {
            float xv = x_lds[b * kc + kk];
            acc[b].x = fmaf(xv, wv.x, acc[b].x);
            acc[b].y = fmaf(xv, wv.y, acc[b].y);
        }
    }
    float* pp = part + (size_t)blockIdx.y * B_ * N + j0;
#pragma unroll
    for (int b = 0; b < B_; ++b)
        *reinterpret_cast<float2*>(pp + (size_t)b * N) = acc[b];
}

// -------------------------------------------- reduce partials + bias + residual
__global__ __launch_bounds__(256) void reduce_bias_res(
    const float* __restrict__ part, int nsplit, int N,
    const float* __restrict__ bias, const float* __restrict__ res,
    float* __restrict__ out, int total)
{
    int i = blockIdx.x * 256 + threadIdx.x;
    if (i >= total) return;
    float s = 0.f;
    for (int p = 0; p < nsplit; ++p) s += part[(size_t)p * total + i];
    int jc = i % N;
    if (bias) s += bias[jc];
    if (res)  s += res[i];
    out[i] = s;
}

// ------------------------------------- reduce partials of gate_up + fused SwiGLU
__global__ __launch_bounds__(256) void reduce_silu(
    const float* __restrict__ part, int nsplit, float* __restrict__ act)
{
    int i = blockIdx.x * 256 + threadIdx.x;
    if (i >= B_ * INTER) return;
    int b = i / INTER;
    int jc = i - b * INTER;
    size_t off = (size_t)b * (2 * INTER) + jc;
    float g = 0.f, u = 0.f;
    for (int p = 0; p < nsplit; ++p) {
        const float* pp = part + (size_t)p * B_ * 2 * INTER;
        g += pp[off];
        u += pp[off + INTER];
    }
    float sg = g / (1.f + expf(-g));
    act[i] = sg * u;
}

// ---------------------------------------------------------------- RoPE (NeoX)
__global__ __launch_bounds__(64) void rope_kernel(
    const float* __restrict__ qkv, const int* __restrict__ positions,
    float* __restrict__ q_rot, float* __restrict__ k_rot, float* __restrict__ v_cp)
{
    int h = blockIdx.x, b = blockIdx.y, i = threadIdx.x;  // i in [0,64)
    float pos = (float)positions[b];
    float freq = powf(10000.0f, -(float)i / 64.0f);
    float ang = pos * freq;
    float sv, cv;
    sincosf(ang, &sv, &cv);
    const float* qb = qkv + (size_t)b * (3 * HID) + h * D_;
    float q1 = qb[i],        q2 = qb[i + 64];
    float k1 = qb[HID + i],  k2 = qb[HID + i + 64];
    size_t o = ((size_t)b * H_ + h) * D_ + i;
    q_rot[o]      = q1 * cv - q2 * sv;
    q_rot[o + 64] = q2 * cv + q1 * sv;
    k_rot[o]      = k1 * cv - k2 * sv;
    k_rot[o + 64] = k2 * cv + k1 * sv;
    v_cp[o]       = qb[2 * HID + i];
    v_cp[o + 64]  = qb[2 * HID + i + 64];
}

// --------------------------------------------------- split-S decode attention
// block per (h, b, chunk); 128 threads; thread t owns output dim d=t.
__global__ __launch_bounds__(128) void attn_split(
    const float* __restrict__ kc, const float* __restrict__ vc,
    const float* __restrict__ q_rot, const float* __restrict__ k_rot,
    const float* __restrict__ v_cp, const int* __restrict__ positions,
    float* __restrict__ pacc, float* __restrict__ pm, float* __restrict__ pl)
{
    int h = blockIdx.x, b = blockIdx.y, c = blockIdx.z, t = threadIdx.x;
    int pos = positions[b];
    int L = pos + 1;
    int j0c = c * CHUNK;
    size_t pidx = (((size_t)b * H_ + h) * NC + c);
    if (j0c >= L) {                 // empty chunk: deterministic zero partials
        if (t == 0) { pm[pidx] = -INFINITY; pl[pidx] = 0.f; }
        pacc[pidx * D_ + t] = 0.f;
        return;
    }
    int jend = min(L, j0c + CHUNK);

    __shared__ float qs[D_];
    __shared__ float ks[32 * 132];  // K tile, padded stride 132 (bank-conflict-free)
    __shared__ float vs[32 * D_];   // V tile
    __shared__ float sc[32];
    qs[t] = q_rot[((size_t)b * H_ + h) * D_ + t];

    float m = -INFINITY, l = 0.f, acc = 0.f;
    const float scaling = 0.08838834764831845f;  // 128^-0.5

    for (int j0 = j0c; j0 < jend; j0 += 32) {
        int nj = min(32, jend - j0);
        __syncthreads();   // prev tile's V reads done before restaging
        for (int idx = t; idx < 32 * 32; idx += 128) {
            int r = idx >> 5, c4 = idx & 31;
            int jj = j0 + r;
            float4 kvv = make_float4(0.f, 0.f, 0.f, 0.f);
            float4 vvv = kvv;
            if (jj < jend) {
                if (jj == pos) {
                    kvv = reinterpret_cast<const float4*>(k_rot + ((size_t)b * H_ + h) * D_)[c4];
                    vvv = reinterpret_cast<const float4*>(v_cp  + ((size_t)b * H_ + h) * D_)[c4];
                } else {
                    kvv = reinterpret_cast<const float4*>(kc + (((size_t)b * S_ + jj) * H_ + h) * D_)[c4];
                    vvv = reinterpret_cast<const float4*>(vc + (((size_t)b * S_ + jj) * H_ + h) * D_)[c4];
                }
            }
            *reinterpret_cast<float4*>(&ks[r * 132 + c4 * 4]) = kvv;
            *reinterpret_cast<float4*>(&vs[r * D_  + c4 * 4]) = vvv;
        }
        __syncthreads();
        {
            int jr = t >> 2, q4 = t & 3;
            const float* kr = ks + jr * 132 + q4 * 32;
            const float* qq = qs + q4 * 32;
            float s = 0.f;
#pragma unroll
            for (int cc = 0; cc < 32; ++cc) s = fmaf(qq[cc], kr[cc], s);
            s += __shfl_xor(s, 1, 64);
            s += __shfl_xor(s, 2, 64);
            if (q4 == 0) sc[jr] = s * scaling;
        }
        __syncthreads();
        float p[32];
        float mt = m;
#pragma unroll
        for (int r = 0; r < 32; ++r) {
            float v = (r < nj) ? sc[r] : -INFINITY;
            p[r] = v;
            mt = fmaxf(mt, v);
        }
        float scale = expf(m - mt);
        float ps = 0.f;
#pragma unroll
        for (int r = 0; r < 32; ++r) {
            float e = (r < nj) ? expf(p[r] - mt) : 0.f;
            p[r] = e;
            ps += e;
        }
        m = mt;
        l = l * scale + ps;
        acc *= scale;
#pragma unroll
        for (int r = 0; r < 32; ++r) acc = fmaf(p[r], vs[r * D_ + t], acc);
    }
    pm[pidx] = m;
    pl[pidx] = l;
    pacc[pidx * D_ + t] = acc;
}

// ------------------------------------------------------- combine chunk partials
__global__ __launch_bounds__(128) void attn_combine(
    const float* __restrict__ pacc, const float* __restrict__ pm,
    const float* __restrict__ pl, float* __restrict__ out)
{
    int h = blockIdx.x, b = blockIdx.y, t = threadIdx.x;
    size_t base = ((size_t)b * H_ + h) * NC;
    float M = -INFINITY;
#pragma unroll
    for (int c = 0; c < NC; ++c) M = fmaxf(M, pm[base + c]);
    float l = 0.f, a = 0.f;
#pragma unroll
    for (int c = 0; c < NC; ++c) {
        float w = expf(pm[base + c] - M);
        l = fmaf(pl[base + c], w, l);
        a = fmaf(pacc[(base + c) * D_ + t], w, a);
    }
    out[((size_t)b * H_ + h) * D_ + t] = a / l;
}

// ---------------------------------------------------------------- launcher
extern "C" void kernel_launch(void* const* d_in, const int* in_sizes, int n_in,
                              void* d_out, int out_size, void* d_ws, size_t ws_size,
                              hipStream_t stream)
{
    const int*   positions = (const int*)  d_in[0];
    const float* hidden    = (const float*)d_in[1];
    const float* kc        = (const float*)d_in[2];
    const float* vc        = (const float*)d_in[3];
    const float* qkv_w     = (const float*)d_in[4];
    const float* qkv_b     = (const float*)d_in[5];
    const float* o_w       = (const float*)d_in[6];
    const float* o_b       = (const float*)d_in[7];
    const float* gu_w      = (const float*)d_in[8];
    const float* down_w    = (const float*)d_in[9];
    const float* ln1       = (const float*)d_in[10];
    const float* ln2       = (const float*)d_in[11];
    float* out = (float*)d_out;
    float* ws  = (float*)d_ws;

    float* x1      = ws;                             // 16*4096
    float* qkv     = x1 + (size_t)B_ * HID;          // 16*12288
    float* q_rot   = qkv + (size_t)B_ * 3 * HID;     // 16*4096
    float* k_rot   = q_rot + (size_t)B_ * HID;
    float* v_cp    = k_rot + (size_t)B_ * HID;
    float* attn_o  = v_cp + (size_t)B_ * HID;
    float* hidden2 = attn_o + (size_t)B_ * HID;
    float* x2      = hidden2 + (size_t)B_ * HID;
    float* act     = x2 + (size_t)B_ * HID;          // 16*11008
    float* part    = act + (size_t)B_ * INTER;       // up to 32*16*4096 & 16*16*12288 floats

    float* pacc = part;                              // B*H*NC*128 = 524288 floats
    float* pm   = pacc + (size_t)B_ * H_ * NC * D_;  // 4096
    float* pl   = pm + (size_t)B_ * H_ * NC;         // 4096

    // 1. RMSNorm 1
    rmsnorm_kernel<<<B_, 256, 0, stream>>>(hidden, ln1, x1);
    // 2. QKV GEMM (K=4096, N=12288): 24 col-blocks x 16 k-splits, kchunk=256
    gemm16_splitk2<<<dim3(24, 16), 256, 16 * 256 * 4, stream>>>(x1, qkv_w, part, HID, 3 * HID, 256);
    reduce_bias_res<<<768, 256, 0, stream>>>(part, 16, 3 * HID, qkv_b, nullptr, qkv, B_ * 3 * HID);
    // 3. RoPE on new q,k (+ copy v)
    rope_kernel<<<dim3(H_, B_), 64, 0, stream>>>(qkv, positions, q_rot, k_rot, v_cp);
    // 4. split-S decode attention + combine
    attn_split<<<dim3(H_, B_, NC), 128, 0, stream>>>(kc, vc, q_rot, k_rot, v_cp, positions,
                                                     pacc, pm, pl);
    attn_combine<<<dim3(H_, B_), 128, 0, stream>>>(pacc, pm, pl, attn_o);
    // 5. O proj (K=4096, N=4096): 8 x 32, kchunk=128, + residual
    gemm16_splitk2<<<dim3(8, 32), 256, 16 * 128 * 4, stream>>>(attn_o, o_w, part, HID, HID, 128);
    reduce_bias_res<<<256, 256, 0, stream>>>(part, 32, HID, o_b, hidden, hidden2, B_ * HID);
    // 6. RMSNorm 2
    rmsnorm_kernel<<<B_, 256, 0, stream>>>(hidden2, ln2, x2);
    // 7. gate_up GEMM (K=4096, N=22016): 43 x 8, kchunk=512, + fused SwiGLU reduce
    gemm16_splitk2<<<dim3(43, 8), 256, 16 * 512 * 4, stream>>>(x2, gu_w, part, HID, 2 * INTER, 512);
    reduce_silu<<<688, 256, 0, stream>>>(part, 8, act);
    // 8. down GEMM (K=11008, N=4096): 8 x 32, kchunk=344, + residual -> out
    gemm16_splitk2<<<dim3(8, 32), 256, 16 * 344 * 4, stream>>>(act, down_w, part, INTER, HID, 344);
    reduce_bias_res<<<256, 256, 0, stream>>>(part, 32, HID, nullptr, hidden2, out, B_ * HID);
}

// Round 4
// 397.289 us; speedup vs baseline: 1.6857x; 1.6857x over previous
//
#include <hip/hip_runtime.h>
#include <cstdint>
#include <cmath>

#define B_    16
#define S_    1024
#define H_    32
#define D_    128
#define HID   4096
#define INTER 11008
#define NC    8         // attention sequence chunks
#define CHUNK 128       // S_/NC

// ---------------------------------------------------------------- RMSNorm
__global__ __launch_bounds__(256) void rmsnorm_kernel(
    const float* __restrict__ in, const float* __restrict__ w, float* __restrict__ out)
{
    int b = blockIdx.x;
    int t = threadIdx.x;
    const float4* row = reinterpret_cast<const float4*>(in + (size_t)b * HID);
    float s = 0.f;
    for (int i = t; i < HID / 4; i += 256) {
        float4 v = row[i];
        s += v.x * v.x + v.y * v.y + v.z * v.z + v.w * v.w;
    }
    for (int off = 32; off; off >>= 1) s += __shfl_down(s, off, 64);
    __shared__ float red[4];
    int wid = t >> 6, lane = t & 63;
    if (lane == 0) red[wid] = s;
    __syncthreads();
    float tot = red[0] + red[1] + red[2] + red[3];
    float rstd = rsqrtf(tot / (float)HID + 1e-6f);
    const float4* wv4 = reinterpret_cast<const float4*>(w);
    float4* o4 = reinterpret_cast<float4*>(out + (size_t)b * HID);
    for (int i = t; i < HID / 4; i += 256) {
        float4 x = row[i], wv = wv4[i];
        float4 r;
        r.x = x.x * rstd * wv.x;
        r.y = x.y * rstd * wv.y;
        r.z = x.z * rstd * wv.z;
        r.w = x.w * rstd * wv.w;
        o4[i] = r;
    }
}

// ---------------------------------------------- skinny GEMM, split-K, float2 cols
// thread owns 2 consecutive output columns (float2 weight loads, 8 B/lane);
// x[b][k] reads are wave-uniform -> compiler scalarizes to s_load (SGPR operand
// folds into v_fma; no LDS, no extra VALU). Grids sized exactly (no bounds check).
__global__ __launch_bounds__(256) void gemm16_splitk2(
    const float* __restrict__ x, const float* __restrict__ w,
    float* __restrict__ part, int K, int N, int kchunk)
{
    int j0 = (blockIdx.x * 256 + threadIdx.x) * 2;
    int k0 = blockIdx.y * kchunk;
    int k1 = k0 + kchunk;
    float2 acc[B_];
#pragma unroll
    for (int b = 0; b < B_; ++b) acc[b] = make_float2(0.f, 0.f);

    const float* wp = w + (size_t)k0 * N + j0;
    for (int k = k0; k < k1; k += 2) {
        float2 wv0 = *reinterpret_cast<const float2*>(wp);
        float2 wv1 = *reinterpret_cast<const float2*>(wp + N);
        wp += 2 * (size_t)N;
#pragma unroll
        for (int b = 0; b < B_; ++b) {
            const float* xb = x + (size_t)b * K + k;   // wave-uniform -> s_load
            float x0 = xb[0], x1 = xb[1];
            acc[b].x = fmaf(x0, wv0.x, acc[b].x);
            acc[b].y = fmaf(x0, wv0.y, acc[b].y);
            acc[b].x = fmaf(x1, wv1.x, acc[b].x);
            acc[b].y = fmaf(x1, wv1.y, acc[b].y);
        }
    }
    float* pp = part + (size_t)blockIdx.y * B_ * N + j0;
#pragma unroll
    for (int b = 0; b < B_; ++b)
        *reinterpret_cast<float2*>(pp + (size_t)b * N) = acc[b];
}

// -------------------------------------------- reduce partials + bias + residual
__global__ __launch_bounds__(256) void reduce_bias_res(
    const float* __restrict__ part, int nsplit, int N,
    const float* __restrict__ bias, const float* __restrict__ res,
    float* __restrict__ out, int total)
{
    int i = blockIdx.x * 256 + threadIdx.x;
    if (i >= total) return;
    float s = 0.f;
    for (int p = 0; p < nsplit; ++p) s += part[(size_t)p * total + i];
    int jc = i % N;
    if (bias) s += bias[jc];
    if (res)  s += res[i];
    out[i] = s;
}

// ------------------------------------- reduce partials of gate_up + fused SwiGLU
__global__ __launch_bounds__(256) void reduce_silu(
    const float* __restrict__ part, int nsplit, float* __restrict__ act)
{
    int i = blockIdx.x * 256 + threadIdx.x;
    if (i >= B_ * INTER) return;
    int b = i / INTER;
    int jc = i - b * INTER;
    size_t off = (size_t)b * (2 * INTER) + jc;
    float g = 0.f, u = 0.f;
    for (int p = 0; p < nsplit; ++p) {
        const float* pp = part + (size_t)p * B_ * 2 * INTER;
        g += pp[off];
        u += pp[off + INTER];
    }
    float sg = g / (1.f + expf(-g));
    act[i] = sg * u;
}

// ---------------------------------------------------------------- RoPE (NeoX)
__global__ __launch_bounds__(64) void rope_kernel(
    const float* __restrict__ qkv, const int* __restrict__ positions,
    float* __restrict__ q_rot, float* __restrict__ k_rot, float* __restrict__ v_cp)
{
    int h = blockIdx.x, b = blockIdx.y, i = threadIdx.x;  // i in [0,64)
    float pos = (float)positions[b];
    float freq = powf(10000.0f, -(float)i / 64.0f);
    float ang = pos * freq;
    float sv, cv;
    sincosf(ang, &sv, &cv);
    const float* qb = qkv + (size_t)b * (3 * HID) + h * D_;
    float q1 = qb[i],        q2 = qb[i + 64];
    float k1 = qb[HID + i],  k2 = qb[HID + i + 64];
    size_t o = ((size_t)b * H_ + h) * D_ + i;
    q_rot[o]      = q1 * cv - q2 * sv;
    q_rot[o + 64] = q2 * cv + q1 * sv;
    k_rot[o]      = k1 * cv - k2 * sv;
    k_rot[o + 64] = k2 * cv + k1 * sv;
    v_cp[o]       = qb[2 * HID + i];
    v_cp[o + 64]  = qb[2 * HID + i + 64];
}

// --------------------------------------------------- split-S decode attention
// block per (h, b, chunk); 128 threads; thread t owns output dim d=t.
__global__ __launch_bounds__(128) void attn_split(
    const float* __restrict__ kc, const float* __restrict__ vc,
    const float* __restrict__ q_rot, const float* __restrict__ k_rot,
    const float* __restrict__ v_cp, const int* __restrict__ positions,
    float* __restrict__ pacc, float* __restrict__ pm, float* __restrict__ pl)
{
    int h = blockIdx.x, b = blockIdx.y, c = blockIdx.z, t = threadIdx.x;
    int pos = positions[b];
    int L = pos + 1;
    int j0c = c * CHUNK;
    size_t pidx = (((size_t)b * H_ + h) * NC + c);
    if (j0c >= L) {                 // empty chunk: deterministic zero partials
        if (t == 0) { pm[pidx] = -INFINITY; pl[pidx] = 0.f; }
        pacc[pidx * D_ + t] = 0.f;
        return;
    }
    int jend = min(L, j0c + CHUNK);

    __shared__ float qs[D_];
    __shared__ float ks[32 * 132];  // K tile, padded stride 132 (bank-conflict-free)
    __shared__ float vs[32 * D_];   // V tile
    __shared__ float sc[32];
    qs[t] = q_rot[((size_t)b * H_ + h) * D_ + t];

    float m = -INFINITY, l = 0.f, acc = 0.f;
    const float scaling = 0.08838834764831845f;  // 128^-0.5

    for (int j0 = j0c; j0 < jend; j0 += 32) {
        int nj = min(32, jend - j0);
        __syncthreads();   // prev tile's V reads done before restaging
        for (int idx = t; idx < 32 * 32; idx += 128) {
            int r = idx >> 5, c4 = idx & 31;
            int jj = j0 + r;
            float4 kvv = make_float4(0.f, 0.f, 0.f, 0.f);
            float4 vvv = kvv;
            if (jj < jend) {
                if (jj == pos) {
                    kvv = reinterpret_cast<const float4*>(k_rot + ((size_t)b * H_ + h) * D_)[c4];
                    vvv = reinterpret_cast<const float4*>(v_cp  + ((size_t)b * H_ + h) * D_)[c4];
                } else {
                    kvv = reinterpret_cast<const float4*>(kc + (((size_t)b * S_ + jj) * H_ + h) * D_)[c4];
                    vvv = reinterpret_cast<const float4*>(vc + (((size_t)b * S_ + jj) * H_ + h) * D_)[c4];
                }
            }
            *reinterpret_cast<float4*>(&ks[r * 132 + c4 * 4]) = kvv;
            *reinterpret_cast<float4*>(&vs[r * D_  + c4 * 4]) = vvv;
        }
        __syncthreads();
        {
            int jr = t >> 2, q4 = t & 3;
            const float* kr = ks + jr * 132 + q4 * 32;
            const float* qq = qs + q4 * 32;
            float s = 0.f;
#pragma unroll
            for (int cc = 0; cc < 32; ++cc) s = fmaf(qq[cc], kr[cc], s);
            s += __shfl_xor(s, 1, 64);
            s += __shfl_xor(s, 2, 64);
            if (q4 == 0) sc[jr] = s * scaling;
        }
        __syncthreads();
        float p[32];
        float mt = m;
#pragma unroll
        for (int r = 0; r < 32; ++r) {
            float v = (r < nj) ? sc[r] : -INFINITY;
            p[r] = v;
            mt = fmaxf(mt, v);
        }
        float scale = expf(m - mt);
        float ps = 0.f;
#pragma unroll
        for (int r = 0; r < 32; ++r) {
            float e = (r < nj) ? expf(p[r] - mt) : 0.f;
            p[r] = e;
            ps += e;
        }
        m = mt;
        l = l * scale + ps;
        acc *= scale;
#pragma unroll
        for (int r = 0; r < 32; ++r) acc = fmaf(p[r], vs[r * D_ + t], acc);
    }
    pm[pidx] = m;
    pl[pidx] = l;
    pacc[pidx * D_ + t] = acc;
}

// ------------------------------------------------------- combine chunk partials
__global__ __launch_bounds__(128) void attn_combine(
    const float* __restrict__ pacc, const float* __restrict__ pm,
    const float* __restrict__ pl, float* __restrict__ out)
{
    int h = blockIdx.x, b = blockIdx.y, t = threadIdx.x;
    size_t base = ((size_t)b * H_ + h) * NC;
    float M = -INFINITY;
#pragma unroll
    for (int c = 0; c < NC; ++c) M = fmaxf(M, pm[base + c]);
    float l = 0.f, a = 0.f;
#pragma unroll
    for (int c = 0; c < NC; ++c) {
        float w = expf(pm[base + c] - M);
        l = fmaf(pl[base + c], w, l);
        a = fmaf(pacc[(base + c) * D_ + t], w, a);
    }
    out[((size_t)b * H_ + h) * D_ + t] = a / l;
}

// ---------------------------------------------------------------- launcher
extern "C" void kernel_launch(void* const* d_in, const int* in_sizes, int n_in,
                              void* d_out, int out_size, void* d_ws, size_t ws_size,
                              hipStream_t stream)
{
    const int*   positions = (const int*)  d_in[0];
    const float* hidden    = (const float*)d_in[1];
    const float* kc        = (const float*)d_in[2];
    const float* vc        = (const float*)d_in[3];
    const float* qkv_w     = (const float*)d_in[4];
    const float* qkv_b     = (const float*)d_in[5];
    const float* o_w       = (const float*)d_in[6];
    const float* o_b       = (const float*)d_in[7];
    const float* gu_w      = (const float*)d_in[8];
    const float* down_w    = (const float*)d_in[9];
    const float* ln1       = (const float*)d_in[10];
    const float* ln2       = (const float*)d_in[11];
    float* out = (float*)d_out;
    float* ws  = (float*)d_ws;

    float* x1      = ws;                             // 16*4096
    float* qkv     = x1 + (size_t)B_ * HID;          // 16*12288
    float* q_rot   = qkv + (size_t)B_ * 3 * HID;     // 16*4096
    float* k_rot   = q_rot + (size_t)B_ * HID;
    float* v_cp    = k_rot + (size_t)B_ * HID;
    float* attn_o  = v_cp + (size_t)B_ * HID;
    float* hidden2 = attn_o + (size_t)B_ * HID;
    float* x2      = hidden2 + (size_t)B_ * HID;
    float* act     = x2 + (size_t)B_ * HID;          // 16*11008
    float* part    = act + (size_t)B_ * INTER;       // up to 64*16*4096 / 32*16*12288 floats

    float* pacc = part;                              // B*H*NC*128 = 524288 floats
    float* pm   = pacc + (size_t)B_ * H_ * NC * D_;  // 4096
    float* pl   = pm + (size_t)B_ * H_ * NC;         // 4096

    // 1. RMSNorm 1
    rmsnorm_kernel<<<B_, 256, 0, stream>>>(hidden, ln1, x1);
    // 2. QKV GEMM (K=4096, N=12288): 24 col-blocks x 32 k-splits (kchunk=128)
    gemm16_splitk2<<<dim3(24, 32), 256, 0, stream>>>(x1, qkv_w, part, HID, 3 * HID, 128);
    reduce_bias_res<<<768, 256, 0, stream>>>(part, 32, 3 * HID, qkv_b, nullptr, qkv, B_ * 3 * HID);
    // 3. RoPE on new q,k (+ copy v)
    rope_kernel<<<dim3(H_, B_), 64, 0, stream>>>(qkv, positions, q_rot, k_rot, v_cp);
    // 4. split-S decode attention + combine
    attn_split<<<dim3(H_, B_, NC), 128, 0, stream>>>(kc, vc, q_rot, k_rot, v_cp, positions,
                                                     pacc, pm, pl);
    attn_combine<<<dim3(H_, B_), 128, 0, stream>>>(pacc, pm, pl, attn_o);
    // 5. O proj (K=4096, N=4096): 8 x 64 (kchunk=64), + residual
    gemm16_splitk2<<<dim3(8, 64), 256, 0, stream>>>(attn_o, o_w, part, HID, HID, 64);
    reduce_bias_res<<<256, 256, 0, stream>>>(part, 64, HID, o_b, hidden, hidden2, B_ * HID);
    // 6. RMSNorm 2
    rmsnorm_kernel<<<B_, 256, 0, stream>>>(hidden2, ln2, x2);
    // 7. gate_up GEMM (K=4096, N=22016): 43 x 16 (kchunk=256), + fused SwiGLU reduce
    gemm16_splitk2<<<dim3(43, 16), 256, 0, stream>>>(x2, gu_w, part, HID, 2 * INTER, 256);
    reduce_silu<<<688, 256, 0, stream>>>(part, 16, act);
    // 8. down GEMM (K=11008, N=4096): 8 x 64 (kchunk=172), + residual -> out
    gemm16_splitk2<<<dim3(8, 64), 256, 0, stream>>>(act, down_w, part, INTER, HID, 172);
    reduce_bias_res<<<256, 256, 0, stream>>>(part, 64, HID, nullptr, hidden2, out, B_ * HID);
}